// Round 1
// baseline (612.219 us; speedup 1.0000x reference)
//
#include <hip/hip_runtime.h>

// Fused Swin-style window attention for MI355X (gfx950).
// B_=8192 windows, N=64 tokens, DIM=128, NH=4 heads, HD=32.
// One block per window, 256 threads = 4 waves = 4 heads.

typedef __attribute__((ext_vector_type(8))) __bf16 bf16x8;
typedef __attribute__((ext_vector_type(4))) float f32x4;
typedef unsigned short u16;
typedef unsigned int u32;

static_assert(sizeof(bf16x8) == 16, "bf16x8 must be 16 bytes");

#define MFMA16(a, b, c) __builtin_amdgcn_mfma_f32_16x16x32_bf16((a), (b), (c), 0, 0, 0)

__device__ __forceinline__ u16 f2bf(float f) {
  u32 u = __builtin_bit_cast(u32, f);
  u += 0x7FFFu + ((u >> 16) & 1u);   // round-to-nearest-even
  return (u16)(u >> 16);
}
__device__ __forceinline__ u32 pack2(float a, float b) {
  return (u32)f2bf(a) | ((u32)f2bf(b) << 16);
}

// ---------------- prep kernels (run once per launch, tiny) ----------------

// Convert qkv_w [384*128] and proj_w [128*128] f32 -> bf16 into workspace.
__global__ void prep_weights(const float* __restrict__ qkv_w,
                             const float* __restrict__ proj_w,
                             u16* __restrict__ wout) {
  int i = blockIdx.x * 256 + threadIdx.x;   // 65536 total
  float v = (i < 49152) ? qkv_w[i] : proj_w[i - 49152];
  wout[i] = f2bf(v);
}

// biasmask[wi][h][i][j] = bias_table[rel_index[i][j]][h] + mask[wi][i][j]  (f32)
__global__ void prep_bm(const float* __restrict__ mask,
                        const float* __restrict__ bias_table,
                        const int* __restrict__ rel_index,
                        float* __restrict__ bm) {
  int idx = blockIdx.x * 256 + threadIdx.x;  // 256*4*64*64 = 4194304
  int j = idx & 63;
  int i = (idx >> 6) & 63;
  int h = (idx >> 12) & 3;
  int wi = idx >> 14;
  int ri = rel_index[i * 64 + j];
  bm[idx] = bias_table[ri * 4 + h] + mask[wi * 4096 + i * 64 + j];
}

// ---------------- main fused kernel ----------------
// LDS map (64 KiB, aliased with barriers):
//   [0,16384)      x (staging)  ->  q [64][128] bf16   -> P lower half
//   [16384,32768)  k [64][128] bf16                    -> P upper half
//     P[h] = smem + h*8192, [64 q][64 k] bf16 (after q/k dead)
//   [32768,49152)  vT [128 dim][64 tok] bf16
//   [49152,65536)  O  [64 tok][128 dim] bf16
// All row-major tiles XOR-swizzled: byte_in_row ^= (row&7)<<4  (bank-conflict fix)

__global__ __launch_bounds__(256, 2)
void win_attn(const float* __restrict__ x,
              const float* __restrict__ qkv_b,
              const float* __restrict__ proj_b,
              const u16* __restrict__ wqkv,    // [384][128] bf16
              const u16* __restrict__ wproj,   // [128][128] bf16
              const float* __restrict__ bm,    // [256][4][64][64] f32
              float* __restrict__ out) {
  __shared__ __align__(16) unsigned char smem[65536];
  const int tid = threadIdx.x;
  const int wid = tid >> 6;
  const int lane = tid & 63;
  const int l15 = lane & 15;
  const int lg = lane >> 4;
  const int b_ = blockIdx.x;
  const int wi = b_ & 255;           // window index within image (mask id)

  // ---- stage x -> LDS bf16, swizzled ----
  {
    const float4* xp = (const float4*)(x + (size_t)b_ * 8192);
#pragma unroll
    for (int it = 0; it < 8; ++it) {
      int f = it * 256 + tid;        // float4 index, 2048 total
      float4 v = xp[f];
      int row = f >> 5;              // 32 float4 per 128-dim row
      u32 addr = (u32)(row * 256) + ((u32)((f & 31) * 8) ^ ((u32)(row & 7) << 4));
      *(uint2*)(smem + addr) = make_uint2(pack2(v.x, v.y), pack2(v.z, v.w));
    }
  }
  __syncthreads();   // x staged

  // ---- load x fragments (A/B layout: lane -> row l&15, k = lg*8..+8) ----
  bf16x8 xf[4][4];   // [token-tile][k-step]
#pragma unroll
  for (int tt = 0; tt < 4; ++tt) {
    int row = tt * 16 + l15;
    u32 rb = (u32)(row * 256);
    u32 sw = (u32)(row & 7) << 4;
#pragma unroll
    for (int kt = 0; kt < 4; ++kt)
      xf[tt][kt] = *(const bf16x8*)(smem + rb + ((u32)(kt * 64 + lg * 16) ^ sw));
  }
  __syncthreads();   // x reads done; LDS free for q/k/vT

  // ---- QKV GEMM: 24 col-tiles of 16; wave w owns tiles [6w, 6w+6) ----
  // tiles 0-7: q (swapped), 8-15: k (swapped), 16-23: v (normal, transposed out)
  {
    f32x4 zero4 = {0.f, 0.f, 0.f, 0.f};
#pragma unroll
    for (int c6 = 0; c6 < 6; ++c6) {
      int ctg = wid * 6 + c6;
      int cb = ctg * 16;
      bf16x8 wf[4];
      const u16* wrow = wqkv + (cb + l15) * 128 + lg * 8;
#pragma unroll
      for (int kt = 0; kt < 4; ++kt)
        wf[kt] = *(const bf16x8*)(wrow + kt * 32);
      f32x4 acc[4];
#pragma unroll
      for (int tt = 0; tt < 4; ++tt) acc[tt] = zero4;
      if (ctg < 16) {
        // swapped: D[wcol][token] -> rows are 4 consecutive qkv cols -> packed write
#pragma unroll
        for (int kt = 0; kt < 4; ++kt)
#pragma unroll
          for (int tt = 0; tt < 4; ++tt)
            acc[tt] = MFMA16(wf[kt], xf[tt][kt], acc[tt]);
        int c0 = cb + lg * 4;
        float b0 = qkv_b[c0], b1 = qkv_b[c0 + 1], b2 = qkv_b[c0 + 2], b3 = qkv_b[c0 + 3];
        u32 base = (ctg < 8) ? 0u : 16384u;
        int dim = (ctg < 8) ? c0 : (c0 - 128);
#pragma unroll
        for (int tt = 0; tt < 4; ++tt) {
          int tok = tt * 16 + l15;
          u32 addr = base + (u32)(tok * 256) + ((u32)(dim * 2) ^ ((u32)(tok & 7) << 4));
          *(uint2*)(smem + addr) =
              make_uint2(pack2(acc[tt][0] + b0, acc[tt][1] + b1),
                         pack2(acc[tt][2] + b2, acc[tt][3] + b3));
        }
      } else {
        // normal: D[token][vcol] -> rows are 4 consecutive tokens -> packed vT write
#pragma unroll
        for (int kt = 0; kt < 4; ++kt)
#pragma unroll
          for (int tt = 0; tt < 4; ++tt)
            acc[tt] = MFMA16(xf[tt][kt], wf[kt], acc[tt]);
        int vc = cb - 256 + l15;          // v col within [0,128)
        float bs = qkv_b[cb + l15];
#pragma unroll
        for (int tt = 0; tt < 4; ++tt) {
          int tok0 = tt * 16 + lg * 4;
          u32 addr = 32768u + (u32)(vc * 128) + ((u32)(tok0 * 2) ^ ((u32)(vc & 7) << 4));
          *(uint2*)(smem + addr) =
              make_uint2(pack2(acc[tt][0] + bs, acc[tt][1] + bs),
                         pack2(acc[tt][2] + bs, acc[tt][3] + bs));
        }
      }
    }
  }
  __syncthreads();   // q,k,vT ready

  // ---- scores: head h = wid;  S = q_h k_h^T * scale + biasmask ----
  const int h = wid;
  bf16x8 aq[4], bk[4];
  {
    u32 db = (u32)((h * 32 + lg * 8) * 2);
#pragma unroll
    for (int t = 0; t < 4; ++t) {
      int tok = t * 16 + l15;
      u32 sw = (u32)(tok & 7) << 4;
      aq[t] = *(const bf16x8*)(smem + (u32)(tok * 256) + (db ^ sw));
      bk[t] = *(const bf16x8*)(smem + 16384u + (u32)(tok * 256) + (db ^ sw));
    }
  }
  __syncthreads();   // all q/k reads done before P overwrites the same region

  f32x4 s[4][4];
  {
    f32x4 zero4 = {0.f, 0.f, 0.f, 0.f};
#pragma unroll
    for (int mt = 0; mt < 4; ++mt)
#pragma unroll
      for (int nt = 0; nt < 4; ++nt)
        s[mt][nt] = zero4;
  }
#pragma unroll
  for (int mt = 0; mt < 4; ++mt)
#pragma unroll
    for (int nt = 0; nt < 4; ++nt)
      s[mt][nt] = MFMA16(aq[mt], bk[nt], s[mt][nt]);

  // scale + bias + mask (exact f32 from precomputed table)
  const float* bmb = bm + (((size_t)wi * 4 + (size_t)h) << 12);
#pragma unroll
  for (int mt = 0; mt < 4; ++mt)
#pragma unroll
    for (int r = 0; r < 4; ++r) {
      int qt = mt * 16 + lg * 4 + r;
      const float* rowp = bmb + qt * 64 + l15;
#pragma unroll
      for (int nt = 0; nt < 4; ++nt)
        s[mt][nt][r] = s[mt][nt][r] * 0.17677669529663687f + rowp[nt * 16];
    }

  // ---- softmax over rows (64 cols = 4 in-lane + 16-lane shfl group) ----
  float rinv[4][4];
#pragma unroll
  for (int mt = 0; mt < 4; ++mt)
#pragma unroll
    for (int r = 0; r < 4; ++r) {
      float m0 = fmaxf(fmaxf(s[mt][0][r], s[mt][1][r]), fmaxf(s[mt][2][r], s[mt][3][r]));
      m0 = fmaxf(m0, __shfl_xor(m0, 1));
      m0 = fmaxf(m0, __shfl_xor(m0, 2));
      m0 = fmaxf(m0, __shfl_xor(m0, 4));
      m0 = fmaxf(m0, __shfl_xor(m0, 8));
      float sum = 0.f;
#pragma unroll
      for (int nt = 0; nt < 4; ++nt) {
        float p = __expf(s[mt][nt][r] - m0);
        s[mt][nt][r] = p;
        sum += p;
      }
      sum += __shfl_xor(sum, 1);
      sum += __shfl_xor(sum, 2);
      sum += __shfl_xor(sum, 4);
      sum += __shfl_xor(sum, 8);
      rinv[mt][r] = __builtin_amdgcn_rcpf(sum);
    }

  // ---- write P (unnormalized, bf16) to per-head private region ----
  {
    u32 pbase = (u32)(h * 8192);
#pragma unroll
    for (int mt = 0; mt < 4; ++mt)
#pragma unroll
      for (int r = 0; r < 4; ++r) {
        int qt = mt * 16 + lg * 4 + r;
        u32 rb = pbase + (u32)(qt * 128);
        u32 sw = (u32)(qt & 7) << 4;
#pragma unroll
        for (int nt = 0; nt < 4; ++nt) {
          int kt2 = nt * 16 + l15;
          *(u16*)(smem + rb + ((u32)(kt2 * 2) ^ sw)) = f2bf(s[mt][nt][r]);
        }
      }
  }
  // (no barrier: P[h] is written and read only by wave h; vT covered above)

  // ---- PV: O_h = P @ v_h, normalized by 1/rowsum at write ----
  bf16x8 ap[4][2], bv[2][2];
  {
    u32 pbase = (u32)(h * 8192);
#pragma unroll
    for (int mt = 0; mt < 4; ++mt) {
      int qtok = mt * 16 + l15;
      u32 sw = (u32)(qtok & 7) << 4;
#pragma unroll
      for (int kt = 0; kt < 2; ++kt)
        ap[mt][kt] = *(const bf16x8*)(smem + pbase + (u32)(qtok * 128) +
                                      ((u32)(kt * 64 + lg * 16) ^ sw));
    }
#pragma unroll
    for (int nt = 0; nt < 2; ++nt) {
      int vc = h * 32 + nt * 16 + l15;
      u32 sw = (u32)(vc & 7) << 4;
#pragma unroll
      for (int kt = 0; kt < 2; ++kt)
        bv[nt][kt] = *(const bf16x8*)(smem + 32768u + (u32)(vc * 128) +
                                      ((u32)(kt * 64 + lg * 16) ^ sw));
    }
  }
  f32x4 o[4][2];
  {
    f32x4 zero4 = {0.f, 0.f, 0.f, 0.f};
#pragma unroll
    for (int mt = 0; mt < 4; ++mt)
#pragma unroll
      for (int nt = 0; nt < 2; ++nt)
        o[mt][nt] = zero4;
  }
#pragma unroll
  for (int kt = 0; kt < 2; ++kt)
#pragma unroll
    for (int mt = 0; mt < 4; ++mt)
#pragma unroll
      for (int nt = 0; nt < 2; ++nt)
        o[mt][nt] = MFMA16(ap[mt][kt], bv[nt][kt], o[mt][nt]);

  // write O (bf16, normalized) to [49152,65536)
#pragma unroll
  for (int mt = 0; mt < 4; ++mt)
#pragma unroll
    for (int r = 0; r < 4; ++r) {
      int qt = mt * 16 + lg * 4 + r;
      u32 rb = 49152u + (u32)(qt * 256);
      u32 sw = (u32)(qt & 7) << 4;
#pragma unroll
      for (int nt = 0; nt < 2; ++nt) {
        int dim = h * 32 + nt * 16 + l15;
        *(u16*)(smem + rb + ((u32)(dim * 2) ^ sw)) = f2bf(o[mt][nt][r] * rinv[mt][r]);
      }
    }
  __syncthreads();   // O ready for all waves

  // ---- proj GEMM: wave w computes out cols [32w, 32w+32) ----
  bf16x8 ao[4][4], bp[2][4];
#pragma unroll
  for (int mt = 0; mt < 4; ++mt) {
    int tok = mt * 16 + l15;
    u32 rb = 49152u + (u32)(tok * 256);
    u32 sw = (u32)(tok & 7) << 4;
#pragma unroll
    for (int kt = 0; kt < 4; ++kt)
      ao[mt][kt] = *(const bf16x8*)(smem + rb + ((u32)(kt * 64 + lg * 16) ^ sw));
  }
#pragma unroll
  for (int ct = 0; ct < 2; ++ct) {
    const u16* wrow = wproj + (wid * 32 + ct * 16 + l15) * 128 + lg * 8;
#pragma unroll
    for (int kt = 0; kt < 4; ++kt)
      bp[ct][kt] = *(const bf16x8*)(wrow + kt * 32);
  }
  f32x4 po[4][2];
  {
    f32x4 zero4 = {0.f, 0.f, 0.f, 0.f};
#pragma unroll
    for (int mt = 0; mt < 4; ++mt)
#pragma unroll
      for (int ct = 0; ct < 2; ++ct)
        po[mt][ct] = zero4;
  }
#pragma unroll
  for (int kt = 0; kt < 4; ++kt)
#pragma unroll
    for (int mt = 0; mt < 4; ++mt)
#pragma unroll
      for (int ct = 0; ct < 2; ++ct)
        po[mt][ct] = MFMA16(ao[mt][kt], bp[ct][kt], po[mt][ct]);

  float pb0 = proj_b[wid * 32 + l15];
  float pb1 = proj_b[wid * 32 + 16 + l15];
  float* ob = out + (size_t)b_ * 8192;
#pragma unroll
  for (int mt = 0; mt < 4; ++mt)
#pragma unroll
    for (int r = 0; r < 4; ++r) {
      int qt = mt * 16 + lg * 4 + r;
      ob[qt * 128 + wid * 32 + l15] = po[mt][0][r] + pb0;
      ob[qt * 128 + wid * 32 + 16 + l15] = po[mt][1][r] + pb1;
    }
}

// ---------------- launch ----------------

extern "C" void kernel_launch(void* const* d_in, const int* in_sizes, int n_in,
                              void* d_out, int out_size, void* d_ws, size_t ws_size,
                              hipStream_t stream) {
  const float* x          = (const float*)d_in[0];   // [8192,64,128]
  const float* mask       = (const float*)d_in[1];   // [256,64,64]
  const float* qkv_w      = (const float*)d_in[2];   // [384,128]
  const float* qkv_b      = (const float*)d_in[3];   // [384]
  const float* proj_w     = (const float*)d_in[4];   // [128,128]
  const float* proj_b     = (const float*)d_in[5];   // [128]
  const float* bias_table = (const float*)d_in[6];   // [225,4]
  const int*   rel_index  = (const int*)d_in[7];     // [64,64]
  float* out = (float*)d_out;

  // workspace layout: [0,131072) weights bf16; [131072, 131072+16MiB) biasmask f32
  u16* wsw = (u16*)d_ws;                         // 65536 bf16 (qkv_w then proj_w)
  float* bmp = (float*)((char*)d_ws + 131072);   // 4194304 f32

  prep_weights<<<256, 256, 0, stream>>>(qkv_w, proj_w, wsw);
  prep_bm<<<16384, 256, 0, stream>>>(mask, bias_table, rel_index, bmp);
  win_attn<<<8192, 256, 0, stream>>>(x, qkv_b, proj_b, wsw, wsw + 49152, bmp, out);
}